// Round 1
// baseline (13352.699 us; speedup 1.0000x reference)
//
#include <hip/hip_runtime.h>
#include <stdint.h>

// Problem constants
#define TSTEPS 300
#define BATCH  1024
#define MB     16            // batch rows per workgroup
#define NWG    (BATCH / MB)  // 64 workgroups
#define FRAGS_L0 36          // 9 ksteps * 4 gate tiles (K = 32(x) + 256(h0))
#define FRAGS_L1 64          // 16 ksteps * 4 gate tiles (K = 256(h0new) + 256(h1))
#define FRAGS_PW (FRAGS_L0 + FRAGS_L1)  // 100 frags per wave

typedef __bf16 bf16x8 __attribute__((ext_vector_type(8)));
typedef float  f32x4  __attribute__((ext_vector_type(4)));

__device__ __forceinline__ uint16_t f2bf(float f) {
  uint32_t u = __builtin_bit_cast(uint32_t, f);
  u += 0x7fffu + ((u >> 16) & 1u);   // RNE
  return (uint16_t)(u >> 16);
}
__device__ __forceinline__ float bf2f(uint16_t h) {
  uint32_t u = ((uint32_t)h) << 16;
  return __builtin_bit_cast(float, u);
}
__device__ __forceinline__ float sigm(float x) { return 1.0f / (1.0f + __expf(-x)); }
__device__ __forceinline__ float tanh_(float x) {
  float e = __expf(2.0f * x);
  return (e - 1.0f) / (e + 1.0f);
}

// ---------------------------------------------------------------------------
// P1: embedding gather + reshape(300,B,25) packed directly into MFMA A-frag
// layout: Xf[((t*64+wg)*64+lane)*8 + jj]  (bf16), lane: m=lane&15 (row),
// k = (lane>>4)*8 + jj  (k<25 valid, else 0)
// ---------------------------------------------------------------------------
__global__ void gather_x(const int* __restrict__ tok, const float* __restrict__ emb,
                         uint16_t* __restrict__ Xf) {
  int idx = blockIdx.x * 256 + threadIdx.x;       // < 300*64*512 = 9,830,400
  int t    = idx >> 15;
  int rem  = idx & 32767;
  int wg   = rem >> 9;
  int e512 = rem & 511;
  int lane = e512 >> 3;
  int jj   = e512 & 7;
  int m = lane & 15, quad = lane >> 4;
  int k = quad * 8 + jj;
  float v = 0.0f;
  if (k < 25) {
    int b = wg * 16 + m;
    int n = (t * 1024 + b) * 25 + k;              // flat index in [300,1024,25]
    int s  = n / 307200;                          // 1024*300
    int r2 = n - s * 307200;
    int bb = r2 / 300;
    int e  = r2 - bb * 300;
    int token = tok[bb * 25 + s];                 // input[bb][s]
    v = emb[(size_t)token * 300 + e];
  }
  Xf[idx] = f2bf(v);
}

// ---------------------------------------------------------------------------
// P2: pack all weights (bf16) into per-wave MFMA B-frag streams.
// Wp[((w*100+frag)*64+lane)*8 + jj]; lane: n=lane&15, k=(lane>>4)*8+jj.
// frag<36: layer0 (ks 0: W_ih0 k<25; ks 1..8: W_hh0). frag>=36: layer1
// (k<256: W_ih1 vs h0; else W_hh1 vs h1). tile nt in {i,f,g,o}: n=nt*256+w*16+nl
// ---------------------------------------------------------------------------
__global__ void pack_w(const float* __restrict__ Wih0, const float* __restrict__ Whh0,
                       const float* __restrict__ Wih1, const float* __restrict__ Whh1,
                       uint16_t* __restrict__ Wp) {
  int idx = blockIdx.x * 256 + threadIdx.x;       // < 16*100*512 = 819,200
  int w   = idx / 51200;
  int rem = idx - w * 51200;
  int frag = rem >> 9;
  int e    = rem & 511;
  int lane = e >> 3, jj = e & 7;
  int nl = lane & 15, quad = lane >> 4;
  int kk = quad * 8 + jj;
  float v;
  if (frag < FRAGS_L0) {
    int ks = frag >> 2, nt = frag & 3;
    int n = nt * 256 + w * 16 + nl;
    if (ks == 0) v = (kk < 25) ? Wih0[n * 25 + kk] : 0.0f;
    else         v = Whh0[n * 256 + (ks - 1) * 32 + kk];
  } else {
    int f1 = frag - FRAGS_L0;
    int ks = f1 >> 2, nt = f1 & 3;
    int n = nt * 256 + w * 16 + nl;
    int k = ks * 32 + kk;
    v = (k < 256) ? Wih1[n * 256 + k] : Whh1[n * 256 + (k - 256)];
  }
  Wp[idx] = f2bf(v);
}

// ---------------------------------------------------------------------------
// Main persistent kernel: 64 blocks x 1024 threads (16 waves). Block = 16 batch
// rows for all 300 steps. Wave w owns gate columns j = w*16 .. w*16+15 and the
// 4 tiles (i,f,g,o). c-state stays in VGPRs; h round-trips LDS as bf16
// (double-buffered, stride 264 to spread banks). 2 barriers/step.
// ---------------------------------------------------------------------------
__global__ __launch_bounds__(1024, 4) void lstm_main(
    const float* __restrict__ h0in, const float* __restrict__ c0in,
    const float* __restrict__ fcw,  const float* __restrict__ fcb,
    const float* __restrict__ decw, const float* __restrict__ decb,
    const float* __restrict__ bih0, const float* __restrict__ bhh0,
    const float* __restrict__ bih1, const float* __restrict__ bhh1,
    const uint16_t* __restrict__ Xf, const uint16_t* __restrict__ Wp,
    float* __restrict__ out) {
  __shared__ uint16_t h0s[2][16][264];
  __shared__ uint16_t h1s[2][16][264];
  __shared__ float fcs[16][10];

  const int wg   = blockIdx.x;
  const int tid  = threadIdx.x;
  const int w    = tid >> 6;
  const int lane = tid & 63;
  const int jl   = lane & 15;
  const int quad = lane >> 4;
  const int jcol = w * 16 + jl;          // owned hidden index (C-tile col)

  // init LDS h (parity 0) from h0 input
  for (int idx = tid; idx < 16 * 256; idx += 1024) {
    int r = idx >> 8, k = idx & 255;
    int b = wg * 16 + r;
    h0s[0][r][k] = f2bf(h0in[(size_t)b * 256 + k]);
    h1s[0][r][k] = f2bf(h0in[262144 + (size_t)b * 256 + k]);
  }
  // c state: lane holds rows quad*4+r, col jcol
  float c0r[4], c1r[4], h0v[4], h1v[4];
#pragma unroll
  for (int r = 0; r < 4; r++) {
    size_t b = wg * 16 + quad * 4 + r;
    c0r[r] = c0in[b * 256 + jcol];
    c1r[r] = c0in[262144 + b * 256 + jcol];
  }
  // biases per gate tile (same for all rows of the tile)
  float bias0[4], bias1[4];
#pragma unroll
  for (int nt = 0; nt < 4; nt++) {
    int n = nt * 256 + jcol;
    bias0[nt] = bih0[n] + bhh0[n];
    bias1[nt] = bih1[n] + bhh1[n];
  }
  __syncthreads();

  const uint4* pw = (const uint4*)Wp + (size_t)(w * FRAGS_PW) * 64 + lane;
  const uint4* px = (const uint4*)Xf;

  int p = 0;
  for (int t = 0; t < TSTEPS; t++) {
    // ---------------- layer 0: gates = x_t @ Wih0^T + h0 @ Whh0^T + b ------
    f32x4 acc[4];
#pragma unroll
    for (int nt = 0; nt < 4; nt++)
      acc[nt] = (f32x4){bias0[nt], bias0[nt], bias0[nt], bias0[nt]};
    {
      bf16x8 afrag = __builtin_bit_cast(bf16x8, px[((size_t)t * 64 + wg) * 64 + lane]);
      bf16x8 bfrag[4];
#pragma unroll
      for (int nt = 0; nt < 4; nt++)
        bfrag[nt] = __builtin_bit_cast(bf16x8, pw[nt * 64]);
#pragma unroll
      for (int ks = 0; ks <= 8; ks++) {
        bf16x8 anext = afrag;
        bf16x8 bnext[4] = {bfrag[0], bfrag[1], bfrag[2], bfrag[3]};
        if (ks < 8) {
          anext = __builtin_bit_cast(bf16x8,
                    *(const uint4*)&h0s[p][jl][ks * 32 + quad * 8]);
#pragma unroll
          for (int nt = 0; nt < 4; nt++)
            bnext[nt] = __builtin_bit_cast(bf16x8, pw[((ks + 1) * 4 + nt) * 64]);
        }
#pragma unroll
        for (int nt = 0; nt < 4; nt++)
          acc[nt] = __builtin_amdgcn_mfma_f32_16x16x32_bf16(afrag, bfrag[nt], acc[nt], 0, 0, 0);
        afrag = anext;
#pragma unroll
        for (int nt = 0; nt < 4; nt++) bfrag[nt] = bnext[nt];
      }
    }
    // layer-0 cell update (rows quad*4+r, col jcol)
#pragma unroll
    for (int r = 0; r < 4; r++) {
      float gi = sigm(acc[0][r]);
      float gf = sigm(acc[1][r]);
      float gg = tanh_(acc[2][r]);
      float go = sigm(acc[3][r]);
      float c = gf * c0r[r] + gi * gg;
      c0r[r] = c;
      float h = go * tanh_(c);
      h0v[r] = h;
      h0s[1 - p][quad * 4 + r][jcol] = f2bf(h);
    }
    __syncthreads();   // h0_new visible

    // ---------------- layer 1: gates = h0_new @ Wih1^T + h1 @ Whh1^T + b ---
#pragma unroll
    for (int nt = 0; nt < 4; nt++)
      acc[nt] = (f32x4){bias1[nt], bias1[nt], bias1[nt], bias1[nt]};
    {
      bf16x8 afrag = __builtin_bit_cast(bf16x8,
                       *(const uint4*)&h0s[1 - p][jl][quad * 8]);
      bf16x8 bfrag[4];
#pragma unroll
      for (int nt = 0; nt < 4; nt++)
        bfrag[nt] = __builtin_bit_cast(bf16x8, pw[(FRAGS_L0 + nt) * 64]);
#pragma unroll
      for (int ks = 0; ks < 16; ks++) {
        bf16x8 anext = afrag;
        bf16x8 bnext[4] = {bfrag[0], bfrag[1], bfrag[2], bfrag[3]};
        if (ks < 15) {
          int ksn = ks + 1;
          const uint16_t* abase = (ksn < 8)
              ? &h0s[1 - p][jl][ksn * 32 + quad * 8]
              : &h1s[p][jl][(ksn - 8) * 32 + quad * 8];
          anext = __builtin_bit_cast(bf16x8, *(const uint4*)abase);
#pragma unroll
          for (int nt = 0; nt < 4; nt++)
            bnext[nt] = __builtin_bit_cast(bf16x8, pw[(FRAGS_L0 + ksn * 4 + nt) * 64]);
        }
#pragma unroll
        for (int nt = 0; nt < 4; nt++)
          acc[nt] = __builtin_amdgcn_mfma_f32_16x16x32_bf16(afrag, bfrag[nt], acc[nt], 0, 0, 0);
        afrag = anext;
#pragma unroll
        for (int nt = 0; nt < 4; nt++) bfrag[nt] = bnext[nt];
      }
    }
    // layer-1 cell update
#pragma unroll
    for (int r = 0; r < 4; r++) {
      float gi = sigm(acc[0][r]);
      float gf = sigm(acc[1][r]);
      float gg = tanh_(acc[2][r]);
      float go = sigm(acc[3][r]);
      float c = gf * c1r[r] + gi * gg;
      c1r[r] = c;
      float h = go * tanh_(c);
      h1v[r] = h;
      h1s[1 - p][quad * 4 + r][jcol] = f2bf(h);
    }
    __syncthreads();   // h1_new visible; also protects next step's overwrites
    p ^= 1;
  }

  // ---------------- epilogue ----------------
  // out layout: decoded.T [2,1024] | h [2,1024,256] | c [2,1024,256]
  float* outH = out + 2048;
  float* outC = out + 2048 + 524288;
#pragma unroll
  for (int r = 0; r < 4; r++) {
    size_t b = wg * 16 + quad * 4 + r;
    outH[b * 256 + jcol]          = h0v[r];
    outH[262144 + b * 256 + jcol] = h1v[r];
    outC[b * 256 + jcol]          = c0r[r];
    outC[262144 + b * 256 + jcol] = c1r[r];
  }
  // fc (only final timestep matters): relu(h1_final @ fc_w^T + fc_b)
  if (tid < 160) {
    int r = tid / 10, ju = tid - r * 10;
    float s = fcb[ju];
    for (int k = 0; k < 256; k++)
      s += bf2f(h1s[p][r][k]) * fcw[ju * 256 + k];
    fcs[r][ju] = fmaxf(s, 0.0f);
  }
  __syncthreads();
  // decoded = fc @ dec_w^T + dec_b, transposed store
  if (tid < 32) {
    int r = tid & 15, m = tid >> 4;
    float d = decb[m];
#pragma unroll
    for (int q = 0; q < 10; q++) d += fcs[r][q] * decw[m * 10 + q];
    out[(size_t)m * 1024 + wg * 16 + r] = d;
  }
}

// ---------------------------------------------------------------------------
extern "C" void kernel_launch(void* const* d_in, const int* in_sizes, int n_in,
                              void* d_out, int out_size, void* d_ws, size_t ws_size,
                              hipStream_t stream) {
  const int*   tok  = (const int*)d_in[0];
  const float* h0   = (const float*)d_in[1];
  const float* c0   = (const float*)d_in[2];
  const float* emb  = (const float*)d_in[3];
  const float* fcw  = (const float*)d_in[4];
  const float* fcb  = (const float*)d_in[5];
  const float* decw = (const float*)d_in[6];
  const float* decb = (const float*)d_in[7];
  const float* Wih0 = (const float*)d_in[8];
  const float* Whh0 = (const float*)d_in[9];
  const float* bih0 = (const float*)d_in[10];
  const float* bhh0 = (const float*)d_in[11];
  const float* Wih1 = (const float*)d_in[12];
  const float* Whh1 = (const float*)d_in[13];
  const float* bih1 = (const float*)d_in[14];
  const float* bhh1 = (const float*)d_in[15];

  uint16_t* Xf  = (uint16_t*)d_ws;       // 9,830,400 bf16 = 19.66 MB
  uint16_t* Wpk = Xf + 9830400;          //   819,200 bf16 =  1.64 MB

  gather_x<<<38400, 256, 0, stream>>>(tok, emb, Xf);
  pack_w<<<3200, 256, 0, stream>>>(Wih0, Whh0, Wih1, Whh1, Wpk);
  lstm_main<<<NWG, 1024, 0, stream>>>(h0, c0, fcw, fcb, decw, decb,
                                      bih0, bhh0, bih1, bhh1, Xf, Wpk,
                                      (float*)d_out);
}